// Round 8
// baseline (2235.942 us; speedup 1.0000x reference)
//
#include <hip/hip_runtime.h>

typedef float f32x4 __attribute__((ext_vector_type(4)));
typedef float f32x2 __attribute__((ext_vector_type(2)));
typedef short s16x8 __attribute__((ext_vector_type(8)));
typedef __bf16 bf16x8 __attribute__((ext_vector_type(8)));

__device__ __forceinline__ unsigned short f2bf(float f) {
    unsigned int u = __builtin_bit_cast(unsigned int, f);
    u += 0x7FFFu + ((u >> 16) & 1u);
    return (unsigned short)(u >> 16);
}

__device__ __forceinline__ f32x4 MFMA(s16x8 a, s16x8 b, f32x4 c) {
    return __builtin_amdgcn_mfma_f32_16x16x32_bf16(
        __builtin_bit_cast(bf16x8, a), __builtin_bit_cast(bf16x8, b), c, 0, 0, 0);
}

__device__ __forceinline__ float sigm(float v) {
    return __builtin_amdgcn_rcpf(1.f + __builtin_amdgcn_exp2f(-1.4426950408889634f * v));
}
__device__ __forceinline__ float tanh_(float v) {
    return 2.f * __builtin_amdgcn_rcpf(1.f + __builtin_amdgcn_exp2f(-2.8853900817779268f * v)) - 1.f;
}

// ---------------- prologue kernels ----------------

__global__ void wc_kernel(const float* __restrict__ Wih1, const float* __restrict__ W_enc,
                          const float* __restrict__ b_enc, float* __restrict__ WC,
                          float* __restrict__ benc) {
    int i = blockIdx.x * 256 + threadIdx.x;
    if (i >= 1024 * 35) return;
    int j = i / 35;
    int f = i - j * 35;
    const float* wr = Wih1 + j * 256;
    float s = 0.f;
    if (f < 34) {
        for (int e = 0; e < 256; ++e) s += wr[e] * W_enc[e * 34 + f];
        WC[j * 34 + f] = s;
    } else {
        for (int e = 0; e < 256; ++e) s += wr[e] * b_enc[e];
        benc[j] = s;
    }
}

// Pack W (row-major [srcRows, srcK]) into per-wave-sequential bf16 B-frag streams:
// linear s16x8 index ((ntb*KK + kk)*G + g)*64 + lane holds
//   W[g0 + g*gStride + ntb*16 + (lane&15)][kk*32 + (lane>>4)*8 + j]  (0 outside bounds)
__global__ void pack_kernel(const float* __restrict__ src, unsigned short* __restrict__ dst,
                            int NTB, int KK, int G, int gStride, int g0, int srcRows, int srcK) {
    int idx = blockIdx.x * 256 + threadIdx.x;
    int total = NTB * KK * G * 64;
    if (idx >= total) return;
    int lane = idx & 63, q = idx >> 6;
    int g = q % G; q /= G;
    int kk = q % KK;
    int ntb = q / KK;
    int row = g0 + g * gStride + ntb * 16 + (lane & 15);
    int kbase = kk * 32 + ((lane >> 4) & 3) * 8;
    s16x8 v;
    #pragma unroll
    for (int j = 0; j < 8; ++j) {
        int k = kbase + j;
        float fv = (row < srcRows && k < srcK) ? src[row * srcK + k] : 0.f;
        v[j] = (short)f2bf(fv);
    }
    *(s16x8*)(dst + (long)idx * 8) = v;
}

__global__ void bias_kernel(const float* bih1, const float* bhh1, const float* benc,
                            const float* bih2, const float* bhh2, const float* b_dec,
                            float* bs1a, float* bs1b, float* bs2, float* bdec) {
    int j = blockIdx.x * 256 + threadIdx.x;
    if (j < 1024) {
        float s = bih1[j] + bhh1[j];
        bs1a[j] = s + benc[j];
        bs1b[j] = s;
        bs2[j] = bih2[j] + bhh2[j];
    }
    if (j < 48) bdec[j] = (j < 34) ? b_dec[j] : 0.f;
}

// ---------------- fused LSTM kernel ----------------

// One LSTM cell over this block's 64 rows. 16 waves (4/SIMD — the R7 lesson: pipes
// were fully serialized at 2 waves/SIMD); each wave owns ONE 16-col n-tile
// (ntb = wave) and runs two sequential gate-pair passes to keep acc at 32 regs:
//   pass0: gates (i, g-gate) -> pc = sigm(i)*tanh(g)      (16 fp32 carried)
//   pass1: gates (f, o)      -> c = sigm(f)*c + pc; h = sigm(o)*tanh(c)
// Single-buffered A/B (TLP covers latency; R4/R6: reg-hungry ILP => spills).
// Weight streams are pass-major: base (pass*16 + ntb) * KK * 128 s16x8.
template<int KKIN, int SIN>
__device__ __forceinline__ void cell_step(
    const unsigned short* __restrict__ Ain,    // LDS, input-phase A, stride SIN shorts
    const unsigned short* __restrict__ Ahid,   // LDS, hidden-phase A, stride 260 shorts
    const s16x8* __restrict__ pWin,            // packed weights, KK=KKIN (pass-major)
    const s16x8* __restrict__ pWhid,           // packed weights, KK=8   (pass-major)
    const float* __restrict__ Lbias,           // LDS, 1024 floats (i,f,g,o blocks)
    float (&cst)[4][4],
    unsigned short* __restrict__ Hout,         // LDS, stride 260 shorts (inactive buffer)
    int wave, int lane, int ln15, int quad)
{
    const int aIn  = ln15 * SIN + quad * 8;
    const int aHid = ln15 * 260 + quad * 8;
    const int col  = wave * 16 + ln15;
    const int hb   = quad * 4 * 260 + col;
    float pc[4][4];
    #pragma unroll
    for (int pass = 0; pass < 2; ++pass) {
        const s16x8* wIn  = pWin  + __builtin_amdgcn_readfirstlane((pass * 16 + wave) * (KKIN * 128));
        const s16x8* wHid = pWhid + __builtin_amdgcn_readfirstlane((pass * 16 + wave) * 1024);
        const float b0 = Lbias[pass * 256 + col];        // i (pass0) / f (pass1)
        const float b1 = Lbias[512 + pass * 256 + col];  // g (pass0) / o (pass1)
        f32x4 acc[2][4];
        #pragma unroll
        for (int mt = 0; mt < 4; ++mt) {
            acc[0][mt] = f32x4{b0, b0, b0, b0};
            acc[1][mt] = f32x4{b1, b1, b1, b1};
        }
        #pragma unroll 1
        for (int u = 0; u < KKIN + 8; ++u) {
            s16x8 A[4], B[2];
            if (u < KKIN) {
                B[0] = wIn[lane + u * 128];
                B[1] = wIn[lane + u * 128 + 64];
                #pragma unroll
                for (int mt = 0; mt < 4; ++mt)
                    A[mt] = *(const s16x8*)(Ain + aIn + u * 32 + mt * (16 * SIN));
            } else {
                const int vh = u - KKIN;
                B[0] = wHid[lane + vh * 128];
                B[1] = wHid[lane + vh * 128 + 64];
                #pragma unroll
                for (int mt = 0; mt < 4; ++mt)
                    A[mt] = *(const s16x8*)(Ahid + aHid + vh * 32 + mt * (16 * 260));
            }
            #pragma unroll
            for (int mt = 0; mt < 4; ++mt) {
                acc[0][mt] = MFMA(A[mt], B[0], acc[0][mt]);
                acc[1][mt] = MFMA(A[mt], B[1], acc[1][mt]);
            }
        }
        if (pass == 0) {
            #pragma unroll
            for (int mt = 0; mt < 4; ++mt)
                #pragma unroll
                for (int r = 0; r < 4; ++r)
                    pc[mt][r] = sigm(acc[0][mt][r]) * tanh_(acc[1][mt][r]);
        } else {
            #pragma unroll
            for (int mt = 0; mt < 4; ++mt) {
                #pragma unroll
                for (int r = 0; r < 4; ++r) {
                    float cn = sigm(acc[0][mt][r]) * cst[mt][r] + pc[mt][r];
                    cst[mt][r] = cn;
                    Hout[hb + (mt * 16 + r) * 260] = f2bf(sigm(acc[1][mt][r]) * tanh_(cn));
                }
            }
        }
    }
    __syncthreads();  // new h visible to next cell
}

__global__ __launch_bounds__(1024, 4) void lstm_fused(
    const float* __restrict__ x,
    const unsigned short* __restrict__ pWC,
    const unsigned short* __restrict__ pWih1,
    const unsigned short* __restrict__ pWhh1,
    const unsigned short* __restrict__ pWih2,
    const unsigned short* __restrict__ pWhh2,
    const unsigned short* __restrict__ pWdec,
    const float* __restrict__ gb1a, const float* __restrict__ gb1b,
    const float* __restrict__ gb2, const float* __restrict__ gbd,
    float* __restrict__ out) {
    extern __shared__ unsigned char smem[];
    unsigned short* h1[2]; unsigned short* h2[2];
    h1[0] = (unsigned short*)smem;            // 4 × 33280 B (stride 260 shorts)
    h1[1] = h1[0] + 64 * 260;
    h2[0] = h1[1] + 64 * 260;
    h2[1] = h2[0] + 64 * 260;
    unsigned short* xbuf = h2[1] + 64 * 260;  // 64×68 bf16 (cols 34..67 zero), 8704 B
    float* dOut = (float*)xbuf;               // 64×48 f32 cumsum accum (aliases xbuf; safe:
                                              // last xbuf read is cell1 of t=9, before 1st dOut write)
    float* Lb1a = (float*)((unsigned char*)smem + 145408);
    float* Lb1b = Lb1a + 1024;
    float* Lb2  = Lb1b + 1024;
    float* Lbd  = Lb2 + 1024;                 // 48 floats

    const int tid = threadIdx.x;
    const int wave = tid >> 6;                // 0..15 == ntb
    const int lane = tid & 63;
    const int ln15 = lane & 15;
    const int quad = lane >> 4;
    const int m0 = blockIdx.x * 64;

    for (int i = tid; i < 8320; i += 1024) { ((int*)h1[0])[i] = 0; ((int*)h2[0])[i] = 0; }
    for (int i = tid; i < 3072; i += 1024) ((int*)xbuf)[i] = 0;
    if (tid < 1024) { Lb1a[tid] = gb1a[tid]; Lb1b[tid] = gb1b[tid]; Lb2[tid] = gb2[tid]; }
    if (tid < 48) Lbd[tid] = gbd[tid];

    float c1[4][4], c2[4][4];
    #pragma unroll
    for (int mt = 0; mt < 4; ++mt)
        #pragma unroll
        for (int r = 0; r < 4; ++r) { c1[mt][r] = 0.f; c2[mt][r] = 0.f; }

    __syncthreads();

    #pragma unroll 1
    for (int t = 0; t < 19; ++t) {
        const int rp = t & 1;        // read parity
        const int wp = rp ^ 1;       // write parity
        if (t < 10) {
            // stage x_t -> xbuf (bf16; cols 34..67 remain zero)
            for (int i = tid; i < 1088; i += 1024) {
                int r = i / 17, p = i - r * 17;
                f32x2 v = __builtin_nontemporal_load((const f32x2*)(x + (m0 + r) * 340 + t * 34) + p);
                unsigned int lo = f2bf(v.x), hi = f2bf(v.y);
                *(unsigned int*)(xbuf + r * 68 + p * 2) = lo | (hi << 16);
            }
            __syncthreads();
            cell_step<2, 68>(xbuf, h1[rp], (const s16x8*)pWC, (const s16x8*)pWhh1,
                             Lb1a, c1, h1[wp], wave, lane, ln15, quad);
        } else {
            cell_step<8, 260>(h2[rp], h1[rp], (const s16x8*)pWih1, (const s16x8*)pWhh1,
                              Lb1b, c1, h1[wp], wave, lane, ln15, quad);
        }
        cell_step<8, 260>(h1[wp], h2[rp], (const s16x8*)pWih2, (const s16x8*)pWhh2,
                          Lb2, c2, h2[wp], wave, lane, ln15, quad);

        if (t >= 9) {
            const int tout = t - 9;
            if (wave < 3) {  // decoder: dec = h2 @ W_dec^T + b_dec; cumsum kept in dOut (LDS)
                const s16x8* wd = (const s16x8*)pWdec + __builtin_amdgcn_readfirstlane(wave * 512);
                const unsigned short* hsrc = h2[wp];
                const int ad = ln15 * 260 + quad * 8;
                f32x4 d[4];
                #pragma unroll
                for (int mt = 0; mt < 4; ++mt) d[mt] = f32x4{0.f, 0.f, 0.f, 0.f};
                #pragma unroll
                for (int kk = 0; kk < 8; ++kk) {
                    s16x8 b = wd[lane + kk * 64];
                    #pragma unroll
                    for (int mt = 0; mt < 4; ++mt) {
                        s16x8 a = *(const s16x8*)(hsrc + ad + kk * 32 + mt * (16 * 260));
                        d[mt] = MFMA(a, b, d[mt]);
                    }
                }
                const int col = wave * 16 + ln15;
                const bool valid = (col < 34);
                const float bd = Lbd[col];
                #pragma unroll
                for (int mt = 0; mt < 4; ++mt) {
                    #pragma unroll
                    for (int r = 0; r < 4; ++r) {
                        const int rloc = mt * 16 + quad * 4 + r;
                        float v = d[mt][r] + bd;
                        if (tout == 0) {
                            float xr = valid ? __builtin_nontemporal_load(x + (m0 + rloc) * 340 + 306 + col) : 0.f;
                            dOut[rloc * 48 + col] = v + xr;
                        } else {
                            dOut[rloc * 48 + col] += v;
                        }
                    }
                }
            }
            __syncthreads();
            // contiguous per-row non-temporal stores (cols 0..33 only)
            for (int i = tid; i < 1088; i += 1024) {
                int r = i / 17, p = i - r * 17;
                f32x2 v = *(const f32x2*)(dOut + r * 48 + p * 2);
                __builtin_nontemporal_store(v, (f32x2*)(out + (m0 + r) * 340 + tout * 34) + p);
            }
            // next writer of dOut is >=2 cell barriers away — no barrier needed here
        }
    }
}

// ---------------- launch ----------------

extern "C" void kernel_launch(void* const* d_in, const int* in_sizes, int n_in,
                              void* d_out, int out_size, void* d_ws, size_t ws_size,
                              hipStream_t stream) {
    const float* x     = (const float*)d_in[0];
    const float* W_enc = (const float*)d_in[1];
    const float* b_enc = (const float*)d_in[2];
    const float* Wih1  = (const float*)d_in[3];
    const float* Whh1  = (const float*)d_in[4];
    const float* bih1  = (const float*)d_in[5];
    const float* bhh1  = (const float*)d_in[6];
    const float* Wih2  = (const float*)d_in[7];
    const float* Whh2  = (const float*)d_in[8];
    const float* bih2  = (const float*)d_in[9];
    const float* bhh2  = (const float*)d_in[10];
    const float* W_dec = (const float*)d_in[11];
    const float* b_dec = (const float*)d_in[12];
    float* out = (float*)d_out;

    unsigned char* w = (unsigned char*)d_ws;
    float* WC   = (float*)(w + 0);         // 139264
    float* benc = (float*)(w + 139264);    // 4096
    float* bs1a = (float*)(w + 143360);
    float* bs1b = (float*)(w + 147456);
    float* bs2  = (float*)(w + 151552);
    float* bdec = (float*)(w + 155648);    // 256
    unsigned short* pWC   = (unsigned short*)(w + 155904);   // 131072 B (2 pass-streams)
    unsigned short* pWih1 = (unsigned short*)(w + 286976);   // 524288 B each (2 pass-streams)
    unsigned short* pWhh1 = (unsigned short*)(w + 811264);
    unsigned short* pWih2 = (unsigned short*)(w + 1335552);
    unsigned short* pWhh2 = (unsigned short*)(w + 1859840);
    unsigned short* pWdec = (unsigned short*)(w + 2384128);  // 24576

    wc_kernel<<<140, 256, 0, stream>>>(Wih1, W_enc, b_enc, WC, benc);
    // gate-pair pass-streams: pass0 rows {i: 0..255, g: 512..767}, pass1 {f: 256..511, o: 768..1023}
    pack_kernel<<<16, 256, 0, stream>>>(WC, pWC,            16, 2, 2, 512, 0,   1024, 34);
    pack_kernel<<<16, 256, 0, stream>>>(WC, pWC + 32768,    16, 2, 2, 512, 256, 1024, 34);
    pack_kernel<<<64, 256, 0, stream>>>(Wih1, pWih1,          16, 8, 2, 512, 0,   1024, 256);
    pack_kernel<<<64, 256, 0, stream>>>(Wih1, pWih1 + 131072, 16, 8, 2, 512, 256, 1024, 256);
    pack_kernel<<<64, 256, 0, stream>>>(Whh1, pWhh1,          16, 8, 2, 512, 0,   1024, 256);
    pack_kernel<<<64, 256, 0, stream>>>(Whh1, pWhh1 + 131072, 16, 8, 2, 512, 256, 1024, 256);
    pack_kernel<<<64, 256, 0, stream>>>(Wih2, pWih2,          16, 8, 2, 512, 0,   1024, 256);
    pack_kernel<<<64, 256, 0, stream>>>(Wih2, pWih2 + 131072, 16, 8, 2, 512, 256, 1024, 256);
    pack_kernel<<<64, 256, 0, stream>>>(Whh2, pWhh2,          16, 8, 2, 512, 0,   1024, 256);
    pack_kernel<<<64, 256, 0, stream>>>(Whh2, pWhh2 + 131072, 16, 8, 2, 512, 256, 1024, 256);
    pack_kernel<<<6, 256, 0, stream>>>(W_dec, pWdec, 3, 8, 1, 0, 0, 34, 256);
    bias_kernel<<<4, 256, 0, stream>>>(bih1, bhh1, benc, bih2, bhh2, b_dec, bs1a, bs1b, bs2, bdec);

    // LDS: 4×33280 (h dbuf) + 12288 (xbuf/dOut) + 3×4096 (biases) + 192 (bdec) = 157888 B
    hipFuncSetAttribute((const void*)lstm_fused, hipFuncAttributeMaxDynamicSharedMemorySize, 157888);
    lstm_fused<<<256, 1024, 157888, stream>>>(x, pWC, pWih1, pWhh1, pWih2, pWhh2, pWdec,
                                              bs1a, bs1b, bs2, bdec, out);
}